// Round 3
// baseline (120.858 us; speedup 1.0000x reference)
//
#include <hip/hip_runtime.h>
#include <math.h>

typedef short bf16x8 __attribute__((ext_vector_type(8)));
typedef float f32x4  __attribute__((ext_vector_type(4)));

#define N_SMPS 16384
#define N_FCNS 2048
#define D_IN 32
#define D_OUT 32
#define KNN 4
#define SPLITS 4
#define CPS 512            // centers per split (one wave per split)
#define TILES 32           // CPS / 16
#define POOL 48            // 8 subsets x top-6, all-distinct candidates
#define SMP 16             // samples per block

__device__ __forceinline__ unsigned umin_u(unsigned a, unsigned b) { return a < b ? a : b; }
__device__ __forceinline__ unsigned umax_u(unsigned a, unsigned b) { return a > b ? a : b; }

// round-to-nearest-even fp32 -> bf16
__device__ __forceinline__ unsigned short bf16_rne(float f) {
  unsigned b = __float_as_uint(f);
  unsigned r = b + 0x7FFFu + ((b >> 16) & 1u);
  return (unsigned short)(r >> 16);
}

// ---------------- ws layout (bytes) ------------------------------------------
// ch 128K | hb 8K   -> 136 KB (wb and xh eliminated: W read as f32 in phase 5,
// x converted block-locally into LDS)
#define OFF_CH   0u
#define OFF_HB   131072u

#define NC4 (N_FCNS * D_IN / 4)            // 16384

// ---------------- Kernel 0: bf16 RNE conversion of ctrs + norms --------------
// Shrunk from 15 MB of traffic to ~0.4 MB: only ch (bf16 ctrs) + hb norms.
__global__ __launch_bounds__(256) void k_prep(
    const float* __restrict__ ctrs,
    unsigned short* __restrict__ ch, float* __restrict__ hb)
{
  const int gt = blockIdx.x * 256 + threadIdx.x;   // 64 blocks -> NC4 threads
  float4 v = ((const float4*)ctrs)[gt];
  ushort4 o;
  o.x = bf16_rne(v.x); o.y = bf16_rne(v.y);
  o.z = bf16_rne(v.z); o.w = bf16_rne(v.w);
  ((ushort4*)ch)[gt] = o;

  if (gt < N_FCNS) {   // fp32-exact half-norms from original ctrs
    const float4* cp4 = (const float4*)(ctrs + (size_t)gt * D_IN);
    float a = 0.f;
    #pragma unroll
    for (int q = 0; q < 8; ++q) {
      float4 c = cp4[q];
      a += c.x * c.x + c.y * c.y + c.z * c.z + c.w * c.w;
    }
    hb[gt] = -0.5f * a;
  }
}

// ---------------- Kernel 1: MEGA -- topk + fp64 refine + gather-apply --------
// Body = the proven 45.6us R0 kernel (256 thr, 4 waves x 512 ctrs, depth-4
// B-frag prefetch), with two local edits:
//  (a) xh is block-local: this block's 16 samples are bf16-converted into
//      1KB of LDS before phase 1; ah comes from one ds_read_b128. Kills the
//      1MB global xh pass in prep.
//  (b) phase 5 reads W directly from wts as f32 float4 (wb eliminated).
//      Same load count as the old uint2 path, minus 256 decode-VALU/thread,
//      and strictly MORE accurate than bf16-rounded W.
__global__ __launch_bounds__(256) void k_mega(
    const unsigned short* __restrict__ ch,
    const float* __restrict__ hb,
    const float* __restrict__ x, const float* __restrict__ ctrs,
    const float* __restrict__ wts, const float* __restrict__ offs,
    float* __restrict__ y)
{
  // arena: phase1 cand = 4*16*16*4 u32 = 16384 B;
  //        phase4/5 diff = 16*4*33 f32 = 8448 B, part = 16*4*8 f32x4 = 8192 B
  __shared__ __align__(16) char u_mem[16640];
  __shared__ float    s_hb[SPLITS * CPS];                      // 8 KB
  __shared__ unsigned s_pool[SMP][POOL];                       // 3 KB
  __shared__ double   s_pd2[SMP][POOL];                        // 6 KB
  __shared__ int      s_pix[SMP][POOL];                        // 3 KB
  __shared__ int      s_sel[SMP][KNN];                         // 256 B
  __shared__ __align__(16) unsigned short s_xh[SMP * D_IN];    // 1 KB

  unsigned* s_cand = (unsigned*)u_mem;          // [w][row][col][e] flattened
  float*    s_diff = (float*)u_mem;             // [sl][j][33] flattened
  float4*   s_part = (float4*)(u_mem + 8448);   // [sl][j][8] flattened

  const int tid = threadIdx.x;
  const int lane = tid & 63;
  const int w = __builtin_amdgcn_readfirstlane(tid >> 6);  // wave = split
  const int col = lane & 15;
  const int quad = lane >> 4;
  const int sbase = blockIdx.x * SMP;
  const int nbase0 = w * CPS;

  // stage this wave's split hb into LDS (coalesced, once)
  #pragma unroll
  for (int r = 0; r < CPS / 64; ++r)
    s_hb[nbase0 + r * 64 + lane] = hb[nbase0 + r * 64 + lane];

  // stage this block's 16 samples as bf16 into LDS (replaces global xh)
  if (tid < 128) {
    const int s = tid >> 3;
    const int q = tid & 7;
    float4 v = ((const float4*)(x + (size_t)(sbase + s) * D_IN))[q];
    ushort4 o;
    o.x = bf16_rne(v.x); o.y = bf16_rne(v.y);
    o.z = bf16_rne(v.z); o.w = bf16_rne(v.w);
    ((ushort4*)s_xh)[tid] = o;
  }

  __syncthreads();   // s_hb + s_xh visible

  // ---- Phase 1: MFMA topk (identical key construction to R0) ----
  const bf16x8 ah = *(const bf16x8*)(s_xh + col * D_IN + quad * 8);

  unsigned ls[4][4];
  #pragma unroll
  for (int r = 0; r < 4; ++r)
    #pragma unroll
    for (int e = 0; e < 4; ++e) ls[r][e] = 0u;   // real keys always > 0

  const unsigned short* chb =
      ch + (size_t)nbase0 * D_IN + (size_t)col * D_IN + quad * 8;
  #define BLOAD(t) (*(const bf16x8*)(chb + (size_t)(t) * 16 * D_IN))
  #define HLOAD(t) (s_hb[nbase0 + (t) * 16 + col])

  bf16x8 bh[4];
  float  hv[4];
  #pragma unroll
  for (int p = 0; p < 4; ++p) { bh[p] = BLOAD(p); hv[p] = HLOAD(p); }

  for (int t = 0; t < TILES; t += 4) {
    #pragma unroll
    for (int p = 0; p < 4; ++p) {
      // process tile t+p from buffer p
      {
        f32x4 acc = {0.f, 0.f, 0.f, 0.f};
        acc = __builtin_amdgcn_mfma_f32_16x16x32_bf16(ah, bh[p], acc, 0, 0, 0);
        const unsigned tc = (unsigned)((t + p) * 16 + col);
        const float hvv = hv[p];
        #pragma unroll
        for (int r = 0; r < 4; ++r) {
          const float uu = acc[r] + hvv;
          unsigned b = __float_as_uint(uu);
          unsigned m = b ^ ((unsigned)((int)b >> 31) | 0x80000000u);
          unsigned key = (m & 0xFFFFFE00u) | tc;
          unsigned t0 = umin_u(ls[r][0], key); ls[r][0] = umax_u(ls[r][0], key);
          unsigned t1 = umin_u(ls[r][1], t0);  ls[r][1] = umax_u(ls[r][1], t0);
          unsigned t2 = umin_u(ls[r][2], t1);  ls[r][2] = umax_u(ls[r][2], t1);
          ls[r][3] = umax_u(ls[r][3], t2);
        }
      }
      // refill buffer p with tile t+4+p (wrap at end; wrapped values unused)
      const int tn = (t + 4 + p) & (TILES - 1);
      bh[p] = BLOAD(tn);
      hv[p] = HLOAD(tn);
    }
  }
  #undef BLOAD
  #undef HLOAD

  #pragma unroll
  for (int r = 0; r < 4; ++r) {
    const int row = quad * 4 + r;
    *(uint4*)&s_cand[(((w * 16) + row) * 16 + col) * 4] =
        make_uint4(ls[r][0], ls[r][1], ls[r][2], ls[r][3]);
  }
  __syncthreads();

  // subset top-6 -> s_pool (same mapping as R0: subset g = wave*2 + half)
  if (tid < 128) {
    const int sl = tid >> 3;
    const int g  = tid & 7;
    const int wv = g >> 1;
    const int chh = (g & 1) * 8;
    unsigned q0 = 0, q1 = 0, q2 = 0, q3 = 0, q4 = 0, q5 = 0;
    #pragma unroll
    for (int c2 = 0; c2 < 8; ++c2) {
      uint4 kv = *(const uint4*)&s_cand[(((wv * 16) + sl) * 16 + chh + c2) * 4];
      unsigned ks[4] = {kv.x, kv.y, kv.z, kv.w};
      #pragma unroll
      for (int e = 0; e < 4; ++e) {
        unsigned key = ks[e];
        unsigned t0 = umin_u(q0, key); q0 = umax_u(q0, key);
        unsigned t1 = umin_u(q1, t0);  q1 = umax_u(q1, t0);
        unsigned t2 = umin_u(q2, t1);  q2 = umax_u(q2, t1);
        unsigned t3 = umin_u(q3, t2);  q3 = umax_u(q3, t2);
        unsigned t4 = umin_u(q4, t3);  q4 = umax_u(q4, t3);
        q5 = umax_u(q5, t4);
      }
    }
    unsigned* op = &s_pool[sl][g * 6];
    op[0] = q0; op[1] = q1; op[2] = q2;
    op[3] = q3; op[4] = q4; op[5] = q5;
  }
  __syncthreads();

  // ---- Phase 2: fp64 exact distances for all 16*48 pool entries ----
  for (int c = tid; c < SMP * POOL; c += 256) {
    const int sl = c / POOL;
    const int p = c - sl * POOL;
    const unsigned key = s_pool[sl][p];
    const int wv = p / 12;
    const int j = wv * CPS + (int)(key & 0x1FFu);
    const float4* xp4 = (const float4*)(x + (size_t)(sbase + sl) * D_IN);
    const float4* cp4 = (const float4*)(ctrs + (size_t)j * D_IN);
    double d2a = 0.0, d2b = 0.0;
    #pragma unroll
    for (int q = 0; q < 8; ++q) {
      float4 cv = cp4[q];
      float4 xv = xp4[q];
      double df0 = (double)xv.x - (double)cv.x;
      double df1 = (double)xv.y - (double)cv.y;
      double df2 = (double)xv.z - (double)cv.z;
      double df3 = (double)xv.w - (double)cv.w;
      d2a = fma(df0, df0, d2a);
      d2b = fma(df1, df1, d2b);
      d2a = fma(df2, df2, d2a);
      d2b = fma(df3, df3, d2b);
    }
    s_pd2[sl][p] = d2a + d2b;
    s_pix[sl][p] = j;
  }
  __syncthreads();

  // ---- Phase 3: per-sample fp64 top-4, np tie-break (proven) ----
  if (tid < SMP) {
    double bd[4]; int b4[4];
    #pragma unroll
    for (int e = 0; e < 4; ++e) { bd[e] = 1e300; b4[e] = 0x7fffffff; }
    for (int m = 0; m < POOL; ++m) {
      const double d2 = s_pd2[tid][m];
      const int j = s_pix[tid][m];
      bool ins = (d2 < bd[3]) || (d2 == bd[3] && j < b4[3]);
      if (ins) {
        bd[3] = d2; b4[3] = j;
        #pragma unroll
        for (int q = 3; q > 0; --q) {
          bool sw = (bd[q] < bd[q - 1]) ||
                    (bd[q] == bd[q - 1] && b4[q] < b4[q - 1]);
          if (sw) {
            double td = bd[q]; bd[q] = bd[q - 1]; bd[q - 1] = td;
            int    tj = b4[q]; b4[q] = b4[q - 1]; b4[q - 1] = tj;
          }
        }
      }
    }
    #pragma unroll
    for (int q = 0; q < 4; ++q) s_sel[tid][q] = b4[q];
  }
  __syncthreads();   // s_cand region dead from here; reuse as diff/part

  // ---- Phase 4: diff staging (overlays dead cand region) ----
  #pragma unroll
  for (int r = 0; r < SMP * KNN * D_IN / 256; ++r) {
    int v = r * 256 + tid;
    int d = v & 31; int p = v >> 5;
    int sl = p >> 2; int j = p & 3;
    int f = s_sel[sl][j];
    s_diff[(sl * KNN + j) * (D_IN + 1) + d] =
        x[(size_t)(sbase + sl) * D_IN + d] - ctrs[(size_t)f * D_IN + d];
  }
  __syncthreads();

  // ---- Phase 5: f32-W gather-apply, 2 slots/thread ----
  #pragma unroll
  for (int r = 0; r < 2; ++r) {
    const int slot = r * 256 + tid;
    const int sl = slot >> 5;
    const int j  = (slot >> 3) & 3;
    const int eq = slot & 7;
    const int f = s_sel[sl][j];
    const float4* wp = (const float4*)(wts + (size_t)f * (D_IN * D_OUT));
    float4 acc = ((const float4*)(offs + (size_t)f * D_OUT))[eq];
    #pragma unroll
    for (int d = 0; d < D_IN; ++d) {
      float4 wv = wp[d * 8 + eq];
      float xc = s_diff[(sl * KNN + j) * (D_IN + 1) + d];
      acc.x = fmaf(xc, wv.x, acc.x);
      acc.y = fmaf(xc, wv.y, acc.y);
      acc.z = fmaf(xc, wv.z, acc.z);
      acc.w = fmaf(xc, wv.w, acc.w);
    }
    s_part[(sl * KNN + j) * 8 + eq] = acc;
  }
  __syncthreads();

  #pragma unroll
  for (int r = 0; r < 2; ++r) {
    const int slot = r * 256 + tid;
    const int sl = slot >> 5;
    const int j  = (slot >> 3) & 3;
    const int eq = slot & 7;
    if (j == 0) {
      float4 a = s_part[(sl * KNN + 0) * 8 + eq];
      float4 b = s_part[(sl * KNN + 1) * 8 + eq];
      float4 c = s_part[(sl * KNN + 2) * 8 + eq];
      float4 e = s_part[(sl * KNN + 3) * 8 + eq];
      float4 o;
      o.x = (a.x + b.x) + (c.x + e.x);
      o.y = (a.y + b.y) + (c.y + e.y);
      o.z = (a.z + b.z) + (c.z + e.z);
      o.w = (a.w + b.w) + (c.w + e.w);
      ((float4*)(y + (size_t)(sbase + sl) * D_OUT))[eq] = o;
    }
  }
}

// ---------------- launch: 2 dispatches ---------------------------------------
extern "C" void kernel_launch(void* const* d_in, const int* in_sizes, int n_in,
                              void* d_out, int out_size, void* d_ws, size_t ws_size,
                              hipStream_t stream) {
  const float* x    = (const float*)d_in[0];
  const float* ctrs = (const float*)d_in[1];
  const float* wts  = (const float*)d_in[2];
  const float* offs = (const float*)d_in[3];
  float* y = (float*)d_out;

  char* ws = (char*)d_ws;
  unsigned short* ch = (unsigned short*)(ws + OFF_CH);
  float*          hb = (float*)(ws + OFF_HB);

  k_prep<<<NC4 / 256, 256, 0, stream>>>(ctrs, ch, hb);
  k_mega<<<N_SMPS / SMP, 256, 0, stream>>>(ch, hb, x, ctrs, wts, offs, y);
}

// Round 4
// 110.975 us; speedup vs baseline: 1.0891x; 1.0891x over previous
//
#include <hip/hip_runtime.h>
#include <math.h>

typedef short bf16x8 __attribute__((ext_vector_type(8)));
typedef float f32x4  __attribute__((ext_vector_type(4)));

#define N_SMPS 16384
#define N_FCNS 2048
#define D_IN 32
#define D_OUT 32
#define KNN 4
#define SPLITS 4
#define CPS 512            // centers per split (one wave per split)
#define TILES 32           // CPS / 16
#define POOL 48            // 8 subsets x top-6, all-distinct candidates
#define PPOOL 49           // padded stride: bank (98*t)%32 = 2t -> conflict-free
#define SMP 16             // samples per block

__device__ __forceinline__ unsigned umin_u(unsigned a, unsigned b) { return a < b ? a : b; }
__device__ __forceinline__ unsigned umax_u(unsigned a, unsigned b) { return a > b ? a : b; }

// round-to-nearest-even fp32 -> bf16
__device__ __forceinline__ unsigned short bf16_rne(float f) {
  unsigned b = __float_as_uint(f);
  unsigned r = b + 0x7FFFu + ((b >> 16) & 1u);
  return (unsigned short)(r >> 16);
}

// ---------------- ws layout (bytes) ------------------------------------------
// ch 128K | hb 8K | wb 4MB  (xh eliminated: x converted block-locally in LDS)
#define OFF_CH   0u
#define OFF_HB   131072u
#define OFF_WB   (OFF_HB + 8192u)

#define NC4 (N_FCNS * D_IN / 4)            // 16384
#define NW4 (N_FCNS * D_IN * D_OUT / 4)    // 524288
#define NTOT (NC4 + NW4)                   // 540672 = 2112 * 256

// ---------------- Kernel 0: bf16 RNE conversion (ctrs, W) + norms ------------
__global__ __launch_bounds__(256) void k_prep(
    const float* __restrict__ ctrs, const float* __restrict__ wts,
    unsigned short* __restrict__ ch, unsigned short* __restrict__ wb,
    float* __restrict__ hb)
{
  const int gt = blockIdx.x * 256 + threadIdx.x;
  const float* src; unsigned short* dst; int i4;
  if (gt < NC4) { src = ctrs; dst = ch; i4 = gt; }
  else          { src = wts;  dst = wb; i4 = gt - NC4; }
  float4 v = ((const float4*)src)[i4];
  ushort4 o;
  o.x = bf16_rne(v.x); o.y = bf16_rne(v.y);
  o.z = bf16_rne(v.z); o.w = bf16_rne(v.w);
  ((ushort4*)dst)[i4] = o;

  if (gt < N_FCNS) {   // fp32-exact half-norms from original ctrs
    const float4* cp4 = (const float4*)(ctrs + (size_t)gt * D_IN);
    float a = 0.f;
    #pragma unroll
    for (int q = 0; q < 8; ++q) {
      float4 c = cp4[q];
      a += c.x * c.x + c.y * c.y + c.z * c.z + c.w * c.w;
    }
    hb[gt] = -0.5f * a;
  }
}

// ---------------- Kernel 1: MEGA -- topk + fp64 refine + gather-apply --------
// Body = the proven 45.6us R0 kernel (256 thr, 4 waves x 512 ctrs, depth-4
// B-frag prefetch, bf16-wb gather-apply), plus three surgical stall-killers:
//  (a) pd2/pix overlaid into u_mem (R1-proven liveness) + block-local s_xh
//      (R3-proven): LDS 37376 -> 29184 -> 5 blocks/CU = 20 waves/CU (+25%).
//  (b) pd2/pix padded to stride 49: phase-3's serial section had ALL 16 lanes
//      on bank 0 (stride 384B) -- the measured 1.16M conflict-cycles.
//  (c) cand col^row XOR swizzle: subset-reduce read 8-way -> conflict-free.
__global__ __launch_bounds__(256) void k_mega(
    const unsigned short* __restrict__ ch,
    const float* __restrict__ hb,
    const float* __restrict__ x, const float* __restrict__ ctrs,
    const unsigned short* __restrict__ wb, const float* __restrict__ offs,
    float* __restrict__ y)
{
  // u_mem timeline:
  //   phase1+reduce : cand [0,16384)
  //   phase2-3      : pd2  [0,6272)   pix [6272,9408)
  //   phase4-5      : diff [0,8448)   part [8448,16640)
  __shared__ __align__(16) char u_mem[16640];
  __shared__ float    s_hb[SPLITS * CPS];                      // 8 KB
  __shared__ unsigned s_pool[SMP][POOL];                       // 3 KB
  __shared__ int      s_sel[SMP][KNN];                         // 256 B
  __shared__ __align__(16) unsigned short s_xh[SMP * D_IN];    // 1 KB

  unsigned* s_cand = (unsigned*)u_mem;          // [w][row][col^row][e]
  double*   s_pd2  = (double*)u_mem;            // [SMP][PPOOL]
  int*      s_pix  = (int*)(u_mem + 6272);      // [SMP][PPOOL]
  float*    s_diff = (float*)u_mem;             // [sl][j][33] flattened
  float4*   s_part = (float4*)(u_mem + 8448);   // [sl][j][8] flattened

  const int tid = threadIdx.x;
  const int lane = tid & 63;
  const int w = __builtin_amdgcn_readfirstlane(tid >> 6);  // wave = split
  const int col = lane & 15;
  const int quad = lane >> 4;
  const int sbase = blockIdx.x * SMP;
  const int nbase0 = w * CPS;

  // stage this wave's split hb into LDS (coalesced, once)
  #pragma unroll
  for (int r = 0; r < CPS / 64; ++r)
    s_hb[nbase0 + r * 64 + lane] = hb[nbase0 + r * 64 + lane];

  // stage this block's 16 samples as bf16 into LDS (replaces global xh)
  if (tid < 128) {
    const int s = tid >> 3;
    const int q = tid & 7;
    float4 v = ((const float4*)(x + (size_t)(sbase + s) * D_IN))[q];
    ushort4 o;
    o.x = bf16_rne(v.x); o.y = bf16_rne(v.y);
    o.z = bf16_rne(v.z); o.w = bf16_rne(v.w);
    ((ushort4*)s_xh)[tid] = o;
  }

  __syncthreads();   // s_hb + s_xh visible

  // ---- Phase 1: MFMA topk (identical key construction to R0) ----
  const bf16x8 ah = *(const bf16x8*)(s_xh + col * D_IN + quad * 8);

  unsigned ls[4][4];
  #pragma unroll
  for (int r = 0; r < 4; ++r)
    #pragma unroll
    for (int e = 0; e < 4; ++e) ls[r][e] = 0u;   // real keys always > 0

  const unsigned short* chb =
      ch + (size_t)nbase0 * D_IN + (size_t)col * D_IN + quad * 8;
  #define BLOAD(t) (*(const bf16x8*)(chb + (size_t)(t) * 16 * D_IN))
  #define HLOAD(t) (s_hb[nbase0 + (t) * 16 + col])

  bf16x8 bh[4];
  float  hv[4];
  #pragma unroll
  for (int p = 0; p < 4; ++p) { bh[p] = BLOAD(p); hv[p] = HLOAD(p); }

  for (int t = 0; t < TILES; t += 4) {
    #pragma unroll
    for (int p = 0; p < 4; ++p) {
      // process tile t+p from buffer p
      {
        f32x4 acc = {0.f, 0.f, 0.f, 0.f};
        acc = __builtin_amdgcn_mfma_f32_16x16x32_bf16(ah, bh[p], acc, 0, 0, 0);
        const unsigned tc = (unsigned)((t + p) * 16 + col);
        const float hvv = hv[p];
        #pragma unroll
        for (int r = 0; r < 4; ++r) {
          const float uu = acc[r] + hvv;
          unsigned b = __float_as_uint(uu);
          unsigned m = b ^ ((unsigned)((int)b >> 31) | 0x80000000u);
          unsigned key = (m & 0xFFFFFE00u) | tc;
          unsigned t0 = umin_u(ls[r][0], key); ls[r][0] = umax_u(ls[r][0], key);
          unsigned t1 = umin_u(ls[r][1], t0);  ls[r][1] = umax_u(ls[r][1], t0);
          unsigned t2 = umin_u(ls[r][2], t1);  ls[r][2] = umax_u(ls[r][2], t1);
          ls[r][3] = umax_u(ls[r][3], t2);
        }
      }
      // refill buffer p with tile t+4+p (wrap at end; wrapped values unused)
      const int tn = (t + 4 + p) & (TILES - 1);
      bh[p] = BLOAD(tn);
      hv[p] = HLOAD(tn);
    }
  }
  #undef BLOAD
  #undef HLOAD

  #pragma unroll
  for (int r = 0; r < 4; ++r) {
    const int row = quad * 4 + r;
    *(uint4*)&s_cand[(((w * 16) + row) * 16 + (col ^ row)) * 4] =
        make_uint4(ls[r][0], ls[r][1], ls[r][2], ls[r][3]);
  }
  __syncthreads();

  // subset top-6 -> s_pool (same mapping as R0: subset g = wave*2 + half)
  if (tid < 128) {
    const int sl = tid >> 3;
    const int g  = tid & 7;
    const int wv = g >> 1;
    const int chh = (g & 1) * 8;
    unsigned q0 = 0, q1 = 0, q2 = 0, q3 = 0, q4 = 0, q5 = 0;
    #pragma unroll
    for (int c2 = 0; c2 < 8; ++c2) {
      uint4 kv = *(const uint4*)
          &s_cand[(((wv * 16) + sl) * 16 + ((chh + c2) ^ sl)) * 4];
      unsigned ks[4] = {kv.x, kv.y, kv.z, kv.w};
      #pragma unroll
      for (int e = 0; e < 4; ++e) {
        unsigned key = ks[e];
        unsigned t0 = umin_u(q0, key); q0 = umax_u(q0, key);
        unsigned t1 = umin_u(q1, t0);  q1 = umax_u(q1, t0);
        unsigned t2 = umin_u(q2, t1);  q2 = umax_u(q2, t1);
        unsigned t3 = umin_u(q3, t2);  q3 = umax_u(q3, t2);
        unsigned t4 = umin_u(q4, t3);  q4 = umax_u(q4, t3);
        q5 = umax_u(q5, t4);
      }
    }
    unsigned* op = &s_pool[sl][g * 6];
    op[0] = q0; op[1] = q1; op[2] = q2;
    op[3] = q3; op[4] = q4; op[5] = q5;
  }
  __syncthreads();   // cand dead from here; u_mem becomes pd2/pix

  // ---- Phase 2: fp64 exact distances for all 16*48 pool entries ----
  for (int c = tid; c < SMP * POOL; c += 256) {
    const int sl = c / POOL;
    const int p = c - sl * POOL;
    const unsigned key = s_pool[sl][p];
    const int wv = p / 12;
    const int j = wv * CPS + (int)(key & 0x1FFu);
    const float4* xp4 = (const float4*)(x + (size_t)(sbase + sl) * D_IN);
    const float4* cp4 = (const float4*)(ctrs + (size_t)j * D_IN);
    double d2a = 0.0, d2b = 0.0;
    #pragma unroll
    for (int q = 0; q < 8; ++q) {
      float4 cv = cp4[q];
      float4 xv = xp4[q];
      double df0 = (double)xv.x - (double)cv.x;
      double df1 = (double)xv.y - (double)cv.y;
      double df2 = (double)xv.z - (double)cv.z;
      double df3 = (double)xv.w - (double)cv.w;
      d2a = fma(df0, df0, d2a);
      d2b = fma(df1, df1, d2b);
      d2a = fma(df2, df2, d2a);
      d2b = fma(df3, df3, d2b);
    }
    s_pd2[sl * PPOOL + p] = d2a + d2b;
    s_pix[sl * PPOOL + p] = j;
  }
  __syncthreads();

  // ---- Phase 3: per-sample fp64 top-4, np tie-break (proven) ----
  if (tid < SMP) {
    double bd[4]; int b4[4];
    #pragma unroll
    for (int e = 0; e < 4; ++e) { bd[e] = 1e300; b4[e] = 0x7fffffff; }
    for (int m = 0; m < POOL; ++m) {
      const double d2 = s_pd2[tid * PPOOL + m];
      const int j = s_pix[tid * PPOOL + m];
      bool ins = (d2 < bd[3]) || (d2 == bd[3] && j < b4[3]);
      if (ins) {
        bd[3] = d2; b4[3] = j;
        #pragma unroll
        for (int q = 3; q > 0; --q) {
          bool sw = (bd[q] < bd[q - 1]) ||
                    (bd[q] == bd[q - 1] && b4[q] < b4[q - 1]);
          if (sw) {
            double td = bd[q]; bd[q] = bd[q - 1]; bd[q - 1] = td;
            int    tj = b4[q]; b4[q] = b4[q - 1]; b4[q - 1] = tj;
          }
        }
      }
    }
    #pragma unroll
    for (int q = 0; q < 4; ++q) s_sel[tid][q] = b4[q];
  }
  __syncthreads();   // pd2/pix dead from here; u_mem becomes diff/part

  // ---- Phase 4: diff staging ----
  #pragma unroll
  for (int r = 0; r < SMP * KNN * D_IN / 256; ++r) {
    int v = r * 256 + tid;
    int d = v & 31; int p = v >> 5;
    int sl = p >> 2; int j = p & 3;
    int f = s_sel[sl][j];
    s_diff[(sl * KNN + j) * (D_IN + 1) + d] =
        x[(size_t)(sbase + sl) * D_IN + d] - ctrs[(size_t)f * D_IN + d];
  }
  __syncthreads();

  // ---- Phase 5: bf16-W gather-apply, 2 slots/thread (proven R0 path) ----
  #pragma unroll
  for (int r = 0; r < 2; ++r) {
    const int slot = r * 256 + tid;
    const int sl = slot >> 5;
    const int j  = (slot >> 3) & 3;
    const int eq = slot & 7;
    const int f = s_sel[sl][j];
    const uint2* wp = (const uint2*)(wb + (size_t)f * (D_IN * D_OUT));
    float4 acc = ((const float4*)(offs + (size_t)f * D_OUT))[eq];
    #pragma unroll
    for (int d = 0; d < D_IN; ++d) {
      uint2 wv = wp[d * 8 + eq];
      float w0 = __uint_as_float(wv.x << 16);
      float w1 = __uint_as_float(wv.x & 0xFFFF0000u);
      float w2 = __uint_as_float(wv.y << 16);
      float w3 = __uint_as_float(wv.y & 0xFFFF0000u);
      float xc = s_diff[(sl * KNN + j) * (D_IN + 1) + d];
      acc.x = fmaf(xc, w0, acc.x);
      acc.y = fmaf(xc, w1, acc.y);
      acc.z = fmaf(xc, w2, acc.z);
      acc.w = fmaf(xc, w3, acc.w);
    }
    s_part[(sl * KNN + j) * 8 + eq] = acc;
  }
  __syncthreads();

  #pragma unroll
  for (int r = 0; r < 2; ++r) {
    const int slot = r * 256 + tid;
    const int sl = slot >> 5;
    const int j  = (slot >> 3) & 3;
    const int eq = slot & 7;
    if (j == 0) {
      float4 a = s_part[(sl * KNN + 0) * 8 + eq];
      float4 b = s_part[(sl * KNN + 1) * 8 + eq];
      float4 c = s_part[(sl * KNN + 2) * 8 + eq];
      float4 e = s_part[(sl * KNN + 3) * 8 + eq];
      float4 o;
      o.x = (a.x + b.x) + (c.x + e.x);
      o.y = (a.y + b.y) + (c.y + e.y);
      o.z = (a.z + b.z) + (c.z + e.z);
      o.w = (a.w + b.w) + (c.w + e.w);
      ((float4*)(y + (size_t)(sbase + sl) * D_OUT))[eq] = o;
    }
  }
}

// ---------------- launch: 2 dispatches ---------------------------------------
extern "C" void kernel_launch(void* const* d_in, const int* in_sizes, int n_in,
                              void* d_out, int out_size, void* d_ws, size_t ws_size,
                              hipStream_t stream) {
  const float* x    = (const float*)d_in[0];
  const float* ctrs = (const float*)d_in[1];
  const float* wts  = (const float*)d_in[2];
  const float* offs = (const float*)d_in[3];
  float* y = (float*)d_out;

  char* ws = (char*)d_ws;
  unsigned short* ch = (unsigned short*)(ws + OFF_CH);
  float*          hb = (float*)(ws + OFF_HB);
  unsigned short* wb = (unsigned short*)(ws + OFF_WB);

  k_prep<<<NTOT / 256, 256, 0, stream>>>(ctrs, wts, ch, wb, hb);
  k_mega<<<N_SMPS / SMP, 256, 0, stream>>>(ch, hb, x, ctrs, wb, offs, y);
}